// Round 10
// baseline (4666.146 us; speedup 1.0000x reference)
//
#include <hip/hip_runtime.h>

#define EMD 0.77880078307140486824  // exp(-1/4)
#define ESD 0.36787944117144232160  // exp(-1)
#define TCG 256                     // g1/iir2 chunk (2 chunks of 512)
#define TCS 128                     // downstream sub-chunk

typedef double d4 __attribute__((ext_vector_type(4)));

// ---------------------------------------------------------------------------
// MFMA f64 16x16x4 C/D-layout probe (verified working in round 9).
// ---------------------------------------------------------------------------
__global__ void mfma_probe(double* __restrict__ flagOut)
{
    const int lane = threadIdx.x & 63;
    const int lr = lane & 15;
    const int lk = lane >> 4;
    const double a = 100.0 * lr + lk + 1.0;
    const double b = 1000.0 * lk + lr + 7.0;
    d4 c = {};
    c = __builtin_amdgcn_mfma_f64_16x16x4f64(a, b, c, 0, 0, 0);
    int myflag = 4;
    for (int h = 3; h >= 0; --h) {
        int ok = 1;
        for (int v = 0; v < 4; ++v) {
            int i, j;
            if (h == 0)      { i = 4 * lk + v; j = lr; }
            else if (h == 1) { i = lk + 4 * v; j = lr; }
            else if (h == 2) { i = lr; j = 4 * lk + v; }
            else             { i = lr; j = lk + 4 * v; }
            double e = 0.0;
            for (int k = 0; k < 4; ++k)
                e += (100.0 * i + k + 1.0) * (1000.0 * k + j + 7.0);
            if (c[v] != e) ok = 0;
        }
        if (__all(ok)) myflag = h;
    }
    if (lane == 0) flagOut[0] = (double)myflag;
}

__device__ __forceinline__ void frag_rc(int flag, int lk, int lr, int v,
                                        int& rl, int& cl)
{
    if (flag == 1)      { rl = lk + 4 * v; cl = lr; }
    else if (flag == 2) { rl = lr; cl = 4 * lk + v; }
    else if (flag == 3) { rl = lr; cl = lk + 4 * v; }
    else                { rl = 4 * lk + v; cl = lr; }
}

// ---------------------------------------------------------------------------
// g1_mfma: block = 4 waves, tile 64f x 128t; wave = 32f x 64t for BOTH mu
// and lv. K=784, 49 k-tiles of 16, double-buffered LDS + reg prefetch.
// A strides 80 f32 (2-way banks), B stride 136 (2-way). k ascending chain.
// ---------------------------------------------------------------------------
__global__ __launch_bounds__(256) void g1_mfma(
    const float* __restrict__ X,    // (64,784,512)
    const float* __restrict__ W1,   // (1000,784)
    const float* __restrict__ B1,   // (1000)
    const float* __restrict__ EPS,  // (64,500,512)
    double* __restrict__ SAMP,      // (64,500,TCG)
    const double* __restrict__ FLG,
    int t0)
{
    const int b   = blockIdx.z;
    const int m0  = blockIdx.y * 64;
    const int tt0 = blockIdx.x * 128;       // within TCG chunk
    const int tg  = t0 + tt0;

    __shared__ float Am[2][16][80];
    __shared__ float Al[2][16][80];
    __shared__ float Bs[2][16][136];

    const int tid  = threadIdx.x;
    const int lane = tid & 63;
    const int wid  = tid >> 6;
    const int wf   = (wid >> 1) * 32;       // {0,32}
    const int wt   = (wid & 1) * 64;        // {0,64}
    const int lr   = lane & 15;
    const int lk   = lane >> 4;

    // staging assignment
    const int sm  = tid >> 2;               // 0..63 f-row
    const int skk = (tid & 3) * 4;          // 0,4,8,12
    int sf = m0 + sm; if (sf > 499) sf = 499;
    const float* wa_ptr = &W1[(size_t)sf * 784 + skk];
    const float* wl_ptr = &W1[(size_t)(500 + sf) * 784 + skk];
    const int sbk = tid >> 4;               // 0..15
    const int sbt = (tid & 15) * 8;
    const float* x_ptr = &X[((size_t)b * 784 + sbk) * 512 + tg + sbt];

    d4 accm[2][4] = {};
    d4 accl[2][4] = {};

    {   // stage k-tile 0 into buffer 0
        const float4 aw = *(const float4*)wa_ptr;
        const float4 lw = *(const float4*)wl_ptr;
        Am[0][skk+0][sm] = aw.x; Am[0][skk+1][sm] = aw.y;
        Am[0][skk+2][sm] = aw.z; Am[0][skk+3][sm] = aw.w;
        Al[0][skk+0][sm] = lw.x; Al[0][skk+1][sm] = lw.y;
        Al[0][skk+2][sm] = lw.z; Al[0][skk+3][sm] = lw.w;
        *(float4*)&Bs[0][sbk][sbt]     = *(const float4*)x_ptr;
        *(float4*)&Bs[0][sbk][sbt + 4] = *(const float4*)(x_ptr + 4);
    }
    __syncthreads();

    for (int it = 0; it < 49; ++it) {
        const int cur = it & 1;
        float4 aw, lw, x0, x1;
        if (it < 48) {                       // prefetch next k-tile to regs
            const int ko = (it + 1) * 16;
            aw = *(const float4*)(wa_ptr + ko);
            lw = *(const float4*)(wl_ptr + ko);
            x0 = *(const float4*)(x_ptr + (size_t)ko * 512);
            x1 = *(const float4*)(x_ptr + (size_t)ko * 512 + 4);
        }
        #pragma unroll
        for (int ks = 0; ks < 4; ++ks) {
            const int kr = 4 * ks + lk;
            const double a0 = (double)Am[cur][kr][wf + lr];
            const double a1 = (double)Am[cur][kr][wf + 16 + lr];
            const double l0 = (double)Al[cur][kr][wf + lr];
            const double l1 = (double)Al[cur][kr][wf + 16 + lr];
            double bb[4];
            #pragma unroll
            for (int h = 0; h < 4; ++h)
                bb[h] = (double)Bs[cur][kr][wt + 16 * h + lr];
            #pragma unroll
            for (int h = 0; h < 4; ++h) {
                accm[0][h] = __builtin_amdgcn_mfma_f64_16x16x4f64(a0, bb[h], accm[0][h], 0, 0, 0);
                accm[1][h] = __builtin_amdgcn_mfma_f64_16x16x4f64(a1, bb[h], accm[1][h], 0, 0, 0);
                accl[0][h] = __builtin_amdgcn_mfma_f64_16x16x4f64(l0, bb[h], accl[0][h], 0, 0, 0);
                accl[1][h] = __builtin_amdgcn_mfma_f64_16x16x4f64(l1, bb[h], accl[1][h], 0, 0, 0);
            }
        }
        __syncthreads();
        if (it < 48) {
            const int nxt = cur ^ 1;
            Am[nxt][skk+0][sm] = aw.x; Am[nxt][skk+1][sm] = aw.y;
            Am[nxt][skk+2][sm] = aw.z; Am[nxt][skk+3][sm] = aw.w;
            Al[nxt][skk+0][sm] = lw.x; Al[nxt][skk+1][sm] = lw.y;
            Al[nxt][skk+2][sm] = lw.z; Al[nxt][skk+3][sm] = lw.w;
            *(float4*)&Bs[nxt][sbk][sbt]     = x0;
            *(float4*)&Bs[nxt][sbk][sbt + 4] = x1;
        }
        __syncthreads();
    }

    const int flag = (int)FLG[0];
    for (int fi = 0; fi < 2; ++fi)
    for (int h = 0; h < 4; ++h)
    for (int v = 0; v < 4; ++v) {
        int rl, cl;
        frag_rc(flag, lk, lr, v, rl, cl);
        const int f = m0 + wf + fi * 16 + rl;
        if (f >= 500) continue;
        const int tloc = tt0 + wt + h * 16 + cl;
        const double bm = (double)B1[f];
        const double bl = (double)B1[500 + f];
        const double mu = fmax(accm[fi][h][v] + bm, 0.0);
        const double lv = fmax(accl[fi][h][v] + bl, 0.0);
        const double e  = (double)EPS[((size_t)b * 500 + f) * 512 + t0 + tloc];
        SAMP[((size_t)b * 500 + f) * TCG + tloc] = mu + e * exp(0.5 * lv);
    }
}

// ---------------------------------------------------------------------------
// iir2: exact sequential dual-exp, in-place on (32000 rows, TCG).
// ---------------------------------------------------------------------------
__global__ __launch_bounds__(256) void iir2_chunk(
    double* __restrict__ A,
    double* __restrict__ stM, double* __restrict__ stS, int first)
{
    __shared__ double tile[64][65];
    const int tid = threadIdx.x;
    const int r0 = blockIdx.x * 64;
    double m = 0.0, s = 0.0;
    if (tid < 64 && !first) { m = stM[r0 + tid]; s = stS[r0 + tid]; }

    for (int sub = 0; sub < TCG / 64; ++sub) {
        #pragma unroll
        for (int q = 0; q < 8; ++q) {
            const int e2 = q * 256 + tid;
            const int r = e2 >> 5;
            const int c = (e2 & 31) * 2;
            const double2 v = *(const double2*)&A[(size_t)(r0 + r) * TCG + sub * 64 + c];
            tile[r][c] = v.x; tile[r][c + 1] = v.y;
        }
        __syncthreads();
        if (tid < 64) {
            #pragma unroll
            for (int c = 0; c < 64; ++c) {
                const double x = tile[tid][c];
                m = EMD * m + x;
                s = ESD * s + x;
                tile[tid][c] = m - s;
            }
        }
        __syncthreads();
        #pragma unroll
        for (int q = 0; q < 8; ++q) {
            const int e2 = q * 256 + tid;
            const int r = e2 >> 5;
            const int c = (e2 & 31) * 2;
            double2 v; v.x = tile[r][c]; v.y = tile[r][c + 1];
            *(double2*)&A[(size_t)(r0 + r) * TCG + sub * 64 + c] = v;
        }
        __syncthreads();
    }
    if (tid < 64) { stM[r0 + tid] = m; stS[r0 + tid] = s; }
}

// ---------------------------------------------------------------------------
// g2_mfma: wx2[tl,b,o] = sum_f a2[b,f,t_off+tl]*W2[o,f] + B2[o].
// Block 64tl x 128o, 4 waves (wave 32tl x 64o). K=500 pad 512, 32 k-tiles,
// double-buffered. At stride 72 f64; Wo stride 136 f32.
// ---------------------------------------------------------------------------
__global__ __launch_bounds__(256) void g2_mfma(
    const double* __restrict__ A2,  // (64,500,TCG)
    const float* __restrict__ W2,   // (500,500)
    const float* __restrict__ B2,   // (500)
    double* __restrict__ WX2,       // (TCS,64,500)
    const double* __restrict__ FLG,
    int t_off)
{
    const int b   = blockIdx.z;
    const int o0  = blockIdx.y * 128;
    const int tl0 = blockIdx.x * 64;

    __shared__ double At[2][16][72];
    __shared__ float  Wo[2][16][136];

    const int tid  = threadIdx.x;
    const int lane = tid & 63;
    const int wid  = tid >> 6;
    const int wtl  = (wid >> 1) * 32;       // {0,32}
    const int wo   = (wid & 1) * 64;        // {0,64}
    const int lr   = lane & 15;
    const int lk   = lane >> 4;

    // staging assignment
    const int akk = tid >> 4;               // 0..15 f-offset
    const int at4 = (tid & 15) * 4;         // tl offset
    const double* a_ptr = &A2[((size_t)b * 500 + akk) * TCG + t_off + tl0 + at4];
    const int woo = tid & 127;              // o offset
    const int wfc = (tid >> 7) * 8;         // f sub-offset {0,8}
    int so = o0 + woo; if (so > 499) so = 499;
    const float* w_ptr = &W2[(size_t)so * 500 + wfc];

    d4 acc[2][4] = {};

    {   // stage k-tile 0 (k0 = 0; all f < 500)
        const double2 v0 = *(const double2*)a_ptr;
        const double2 v1 = *(const double2*)(a_ptr + 2);
        *(double2*)&At[0][akk][at4]     = v0;
        *(double2*)&At[0][akk][at4 + 2] = v1;
        const float4 w0 = *(const float4*)w_ptr;
        const float4 w1 = *(const float4*)(w_ptr + 4);
        Wo[0][wfc+0][woo] = w0.x; Wo[0][wfc+1][woo] = w0.y;
        Wo[0][wfc+2][woo] = w0.z; Wo[0][wfc+3][woo] = w0.w;
        Wo[0][wfc+4][woo] = w1.x; Wo[0][wfc+5][woo] = w1.y;
        Wo[0][wfc+6][woo] = w1.z; Wo[0][wfc+7][woo] = w1.w;
    }
    __syncthreads();

    for (int it = 0; it < 32; ++it) {
        const int cur = it & 1;
        double2 v0, v1; float wr[8];
        if (it < 31) {
            const int k0n = (it + 1) * 16;
            if (k0n + akk < 500) {
                v0 = *(const double2*)(a_ptr + (size_t)k0n * TCG);
                v1 = *(const double2*)(a_ptr + (size_t)k0n * TCG + 2);
            } else { v0.x = v0.y = v1.x = v1.y = 0.0; }
            if (k0n + wfc + 7 < 500) {
                const float4 w0 = *(const float4*)(w_ptr + k0n);
                const float4 w1 = *(const float4*)(w_ptr + k0n + 4);
                wr[0]=w0.x; wr[1]=w0.y; wr[2]=w0.z; wr[3]=w0.w;
                wr[4]=w1.x; wr[5]=w1.y; wr[6]=w1.z; wr[7]=w1.w;
            } else {
                #pragma unroll
                for (int c = 0; c < 8; ++c)
                    wr[c] = (k0n + wfc + c < 500) ? w_ptr[k0n + c] : 0.0f;
            }
        }
        #pragma unroll
        for (int ks = 0; ks < 4; ++ks) {
            const int kr = 4 * ks + lk;
            const double a0 = At[cur][kr][wtl + lr];
            const double a1 = At[cur][kr][wtl + 16 + lr];
            double ww[4];
            #pragma unroll
            for (int h = 0; h < 4; ++h)
                ww[h] = (double)Wo[cur][kr][wo + 16 * h + lr];
            #pragma unroll
            for (int h = 0; h < 4; ++h) {
                acc[0][h] = __builtin_amdgcn_mfma_f64_16x16x4f64(a0, ww[h], acc[0][h], 0, 0, 0);
                acc[1][h] = __builtin_amdgcn_mfma_f64_16x16x4f64(a1, ww[h], acc[1][h], 0, 0, 0);
            }
        }
        __syncthreads();
        if (it < 31) {
            const int nxt = cur ^ 1;
            *(double2*)&At[nxt][akk][at4]     = v0;
            *(double2*)&At[nxt][akk][at4 + 2] = v1;
            Wo[nxt][wfc+0][woo] = wr[0]; Wo[nxt][wfc+1][woo] = wr[1];
            Wo[nxt][wfc+2][woo] = wr[2]; Wo[nxt][wfc+3][woo] = wr[3];
            Wo[nxt][wfc+4][woo] = wr[4]; Wo[nxt][wfc+5][woo] = wr[5];
            Wo[nxt][wfc+6][woo] = wr[6]; Wo[nxt][wfc+7][woo] = wr[7];
        }
        __syncthreads();
    }

    const int flag = (int)FLG[0];
    for (int fi = 0; fi < 2; ++fi)
    for (int h = 0; h < 4; ++h)
    for (int v = 0; v < 4; ++v) {
        int rl, cl;
        frag_rc(flag, lk, lr, v, rl, cl);
        const int tl = tl0 + wtl + fi * 16 + rl;
        const int o  = o0 + wo + h * 16 + cl;
        if (o < 500)
            WX2[((size_t)tl * 64 + b) * 500 + o] = acc[fi][h][v] + (double)B2[o];
    }
}

// ---------------------------------------------------------------------------
// LIF2 + IIR3 fused, in-place on (TCS, 32000); carries (v, sp, m, s).
// ---------------------------------------------------------------------------
__global__ __launch_bounds__(256) void lif2iir3_chunk(
    double* __restrict__ WX,
    double* __restrict__ stV, double* __restrict__ stSp,
    double* __restrict__ stM, double* __restrict__ stS, int first)
{
    const int idx = blockIdx.x * 256 + threadIdx.x;
    if (idx >= 32000) return;
    double v, sp, m, s;
    if (first) { v = 0.0; sp = 0.0; m = 0.0; s = 0.0; }
    else { v = stV[idx]; sp = stSp[idx]; m = stM[idx]; s = stS[idx]; }
    for (int tt = 0; tt < TCS; ++tt) {
        const double cur = WX[(size_t)tt * 32000 + idx];
        v = EMD * v * (1.0 - sp) + cur;
        sp = (v >= 1.0) ? 1.0 : 0.0;
        m = EMD * m + sp;
        s = ESD * s + sp;
        WX[(size_t)tt * 32000 + idx] = m - s;
    }
    stV[idx] = v; stSp[idx] = sp; stM[idx] = m; stS[idx] = s;
}

// ---------------------------------------------------------------------------
// g3: one wave per R; lanes split K, 10 outputs tree-reduced via shfl_xor.
// ---------------------------------------------------------------------------
__global__ __launch_bounds__(256) void g3_chunk(
    const double* __restrict__ A3,  // (64*TCS, 500)
    const float* __restrict__ W3,   // (10,500)
    const float* __restrict__ B3,   // (10)
    double* __restrict__ WX3)       // (64*TCS, 10)
{
    __shared__ float w3s[5000];
    for (int i = threadIdx.x; i < 5000; i += 256) w3s[i] = W3[i];
    __syncthreads();

    const int lane = threadIdx.x & 63;
    const int R = blockIdx.x * 4 + (threadIdx.x >> 6);   // 0..8191
    const double* row = A3 + (size_t)R * 500;

    double p[10] = {};
    #pragma unroll
    for (int c = 0; c < 8; ++c) {
        const int i = c * 64 + lane;
        const int ii = (i < 500) ? i : 0;
        const double x = (i < 500) ? row[ii] : 0.0;
        #pragma unroll
        for (int o = 0; o < 10; ++o)
            p[o] = fma(x, (double)w3s[o * 500 + ii], p[o]);
    }
    #pragma unroll
    for (int off = 32; off; off >>= 1)
        #pragma unroll
        for (int o = 0; o < 10; ++o)
            p[o] += __shfl_xor(p[o], off, 64);
    if (lane < 10)
        WX3[(size_t)R * 10 + lane] = p[lane] + (double)B3[lane];
}

// ---------------------------------------------------------------------------
// lif3: (tt*640+idx) -> OUT[idx*512 + t0+tt]; carries (v, sp).
// ---------------------------------------------------------------------------
__global__ __launch_bounds__(256) void lif3_chunk(
    const double* __restrict__ WX3, float* __restrict__ OUT,
    double* __restrict__ stV, double* __restrict__ stSp, int first, int t0)
{
    const int idx = blockIdx.x * 256 + threadIdx.x;
    if (idx >= 640) return;
    double v = first ? 0.0 : stV[idx];
    double sp = first ? 0.0 : stSp[idx];
    for (int tt = 0; tt < TCS; ++tt) {
        const double cur = WX3[(size_t)tt * 640 + idx];
        v = EMD * v * (1.0 - sp) + cur;
        sp = (v >= 1.0) ? 1.0 : 0.0;
        OUT[(size_t)idx * 512 + t0 + tt] = (float)sp;
    }
    stV[idx] = v; stSp[idx] = sp;
}

__global__ void sent_kernel(float* __restrict__ OUT, float v) { OUT[0] = v; }

// ---------------------------------------------------------------------------
extern "C" void kernel_launch(void* const* d_in, const int* in_sizes, int n_in,
                              void* d_out, int out_size, void* d_ws, size_t ws_size,
                              hipStream_t stream)
{
    float* OUT = (float*)d_out;

    const int expect[8] = {25690112, 16384000, 784000, 1000, 250000, 500, 5000, 10};
    int bad = -1;
    if (n_in != 8) bad = 0;
    else {
        for (int k = 0; k < 8; ++k)
            if (in_sizes[k] != expect[k]) { bad = 1 + k; break; }
        if (bad < 0 && out_size != 327680) bad = 9;
        if (bad < 0 && ws_size < (size_t)131072000) bad = 10;
    }
    if (bad >= 0) {
        sent_kernel<<<1, 1, 0, stream>>>(OUT, 4100.0f + bad);
        return;
    }

    const float* X   = (const float*)d_in[0];
    const float* EPS = (const float*)d_in[1];
    const float* W1  = (const float*)d_in[2];
    const float* B1  = (const float*)d_in[3];
    const float* W2  = (const float*)d_in[4];
    const float* B2  = (const float*)d_in[5];
    const float* W3  = (const float*)d_in[6];
    const float* B3  = (const float*)d_in[7];

    double* ws = (double*)d_ws;
    double* buf1  = ws;               // (64,500,TCG)  8,192,000 doubles
    double* buf2  = ws + 8192000;     // (TCS,64,500)  4,096,000
    double* buf4  = ws + 12288000;    // (64*TCS,10)      81,920
    double* stM2  = ws + 12400000;    // 32,000 each
    double* stS2  = ws + 12432000;
    double* stV2  = ws + 12464000;
    double* stSp2 = ws + 12496000;
    double* stM3  = ws + 12528000;
    double* stS3  = ws + 12560000;
    double* stV3  = ws + 12592000;    // 640 each
    double* stSp3 = ws + 12593000;
    double* FLG   = ws + 12600000;    // MFMA layout flag

    mfma_probe<<<1, 64, 0, stream>>>(FLG);

    for (int tc = 0; tc < 512 / TCG; ++tc) {
        const int t0 = tc * TCG;
        const int firstc = (tc == 0) ? 1 : 0;
        g1_mfma<<<dim3(TCG / 128, 8, 64), 256, 0, stream>>>(X, W1, B1, EPS, buf1, FLG, t0);
        iir2_chunk<<<500, 256, 0, stream>>>(buf1, stM2, stS2, firstc);
        for (int h = 0; h < TCG / TCS; ++h) {
            const int first = (firstc && h == 0) ? 1 : 0;
            g2_mfma<<<dim3(TCS / 64, 4, 64), 256, 0, stream>>>(buf1, W2, B2, buf2, FLG, h * TCS);
            lif2iir3_chunk<<<125, 256, 0, stream>>>(buf2, stV2, stSp2, stM3, stS3, first);
            g3_chunk<<<2048, 256, 0, stream>>>(buf2, W3, B3, buf4);
            lif3_chunk<<<3, 256, 0, stream>>>(buf4, OUT, stV3, stSp3, first, t0 + h * TCS);
        }
    }
}

// Round 11
// 4622.568 us; speedup vs baseline: 1.0094x; 1.0094x over previous
//
#include <hip/hip_runtime.h>

#define EMD 0.77880078307140486824  // exp(-1/4)
#define ESD 0.36787944117144232160  // exp(-1)
#define TCG 256                     // g1/iir2 chunk (2 chunks of 512)
#define TCS 128                     // downstream sub-chunk

typedef double d4 __attribute__((ext_vector_type(4)));

// ---------------------------------------------------------------------------
// MFMA f64 16x16x4 C/D-layout probe (verified working in round 9).
// ---------------------------------------------------------------------------
__global__ void mfma_probe(double* __restrict__ flagOut)
{
    const int lane = threadIdx.x & 63;
    const int lr = lane & 15;
    const int lk = lane >> 4;
    const double a = 100.0 * lr + lk + 1.0;
    const double b = 1000.0 * lk + lr + 7.0;
    d4 c = {};
    c = __builtin_amdgcn_mfma_f64_16x16x4f64(a, b, c, 0, 0, 0);
    int myflag = 4;
    for (int h = 3; h >= 0; --h) {
        int ok = 1;
        for (int v = 0; v < 4; ++v) {
            int i, j;
            if (h == 0)      { i = 4 * lk + v; j = lr; }
            else if (h == 1) { i = lk + 4 * v; j = lr; }
            else if (h == 2) { i = lr; j = 4 * lk + v; }
            else             { i = lr; j = lk + 4 * v; }
            double e = 0.0;
            for (int k = 0; k < 4; ++k)
                e += (100.0 * i + k + 1.0) * (1000.0 * k + j + 7.0);
            if (c[v] != e) ok = 0;
        }
        if (__all(ok)) myflag = h;
    }
    if (lane == 0) flagOut[0] = (double)myflag;
}

__device__ __forceinline__ void frag_rc(int flag, int lk, int lr, int v,
                                        int& rl, int& cl)
{
    if (flag == 1)      { rl = lk + 4 * v; cl = lr; }
    else if (flag == 2) { rl = lr; cl = 4 * lk + v; }
    else if (flag == 3) { rl = lr; cl = lk + 4 * v; }
    else                { rl = 4 * lk + v; cl = lr; }
}

// ---------------------------------------------------------------------------
// g1_mfma: block = 4 waves, tile 64f x 128t; wave = 32f x 64t for BOTH mu
// and lv. K=784, 49 k-tiles of 16, double-buffered LDS + reg prefetch.
// __launch_bounds__(256,2): 2 waves/SIMD -> 256-VGPR budget; the ~190-reg
// working set (128 acc + operands + prefetch) must NOT spill (round-10
// lesson: default cap 128 VGPR -> scratch spill -> 6.6 GB/dispatch writes).
// ---------------------------------------------------------------------------
__global__ __launch_bounds__(256, 2) void g1_mfma(
    const float* __restrict__ X,    // (64,784,512)
    const float* __restrict__ W1,   // (1000,784)
    const float* __restrict__ B1,   // (1000)
    const float* __restrict__ EPS,  // (64,500,512)
    double* __restrict__ SAMP,      // (64,500,TCG)
    const double* __restrict__ FLG,
    int t0)
{
    const int b   = blockIdx.z;
    const int m0  = blockIdx.y * 64;
    const int tt0 = blockIdx.x * 128;       // within TCG chunk
    const int tg  = t0 + tt0;

    __shared__ float Am[2][16][80];
    __shared__ float Al[2][16][80];
    __shared__ float Bs[2][16][136];

    const int tid  = threadIdx.x;
    const int lane = tid & 63;
    const int wid  = tid >> 6;
    const int wf   = (wid >> 1) * 32;       // {0,32}
    const int wt   = (wid & 1) * 64;        // {0,64}
    const int lr   = lane & 15;
    const int lk   = lane >> 4;

    // staging assignment
    const int sm  = tid >> 2;               // 0..63 f-row
    const int skk = (tid & 3) * 4;          // 0,4,8,12
    int sf = m0 + sm; if (sf > 499) sf = 499;
    const float* wa_ptr = &W1[(size_t)sf * 784 + skk];
    const float* wl_ptr = &W1[(size_t)(500 + sf) * 784 + skk];
    const int sbk = tid >> 4;               // 0..15
    const int sbt = (tid & 15) * 8;
    const float* x_ptr = &X[((size_t)b * 784 + sbk) * 512 + tg + sbt];

    d4 accm[2][4] = {};
    d4 accl[2][4] = {};

    {   // stage k-tile 0 into buffer 0
        const float4 aw = *(const float4*)wa_ptr;
        const float4 lw = *(const float4*)wl_ptr;
        Am[0][skk+0][sm] = aw.x; Am[0][skk+1][sm] = aw.y;
        Am[0][skk+2][sm] = aw.z; Am[0][skk+3][sm] = aw.w;
        Al[0][skk+0][sm] = lw.x; Al[0][skk+1][sm] = lw.y;
        Al[0][skk+2][sm] = lw.z; Al[0][skk+3][sm] = lw.w;
        *(float4*)&Bs[0][sbk][sbt]     = *(const float4*)x_ptr;
        *(float4*)&Bs[0][sbk][sbt + 4] = *(const float4*)(x_ptr + 4);
    }
    __syncthreads();

    for (int it = 0; it < 49; ++it) {
        const int cur = it & 1;
        float4 aw, lw, x0, x1;
        if (it < 48) {                       // prefetch next k-tile to regs
            const int ko = (it + 1) * 16;
            aw = *(const float4*)(wa_ptr + ko);
            lw = *(const float4*)(wl_ptr + ko);
            x0 = *(const float4*)(x_ptr + (size_t)ko * 512);
            x1 = *(const float4*)(x_ptr + (size_t)ko * 512 + 4);
        }
        #pragma unroll
        for (int ks = 0; ks < 4; ++ks) {
            const int kr = 4 * ks + lk;
            const double a0 = (double)Am[cur][kr][wf + lr];
            const double a1 = (double)Am[cur][kr][wf + 16 + lr];
            const double l0 = (double)Al[cur][kr][wf + lr];
            const double l1 = (double)Al[cur][kr][wf + 16 + lr];
            double bb[4];
            #pragma unroll
            for (int h = 0; h < 4; ++h)
                bb[h] = (double)Bs[cur][kr][wt + 16 * h + lr];
            #pragma unroll
            for (int h = 0; h < 4; ++h) {
                accm[0][h] = __builtin_amdgcn_mfma_f64_16x16x4f64(a0, bb[h], accm[0][h], 0, 0, 0);
                accm[1][h] = __builtin_amdgcn_mfma_f64_16x16x4f64(a1, bb[h], accm[1][h], 0, 0, 0);
                accl[0][h] = __builtin_amdgcn_mfma_f64_16x16x4f64(l0, bb[h], accl[0][h], 0, 0, 0);
                accl[1][h] = __builtin_amdgcn_mfma_f64_16x16x4f64(l1, bb[h], accl[1][h], 0, 0, 0);
            }
        }
        __syncthreads();
        if (it < 48) {
            const int nxt = cur ^ 1;
            Am[nxt][skk+0][sm] = aw.x; Am[nxt][skk+1][sm] = aw.y;
            Am[nxt][skk+2][sm] = aw.z; Am[nxt][skk+3][sm] = aw.w;
            Al[nxt][skk+0][sm] = lw.x; Al[nxt][skk+1][sm] = lw.y;
            Al[nxt][skk+2][sm] = lw.z; Al[nxt][skk+3][sm] = lw.w;
            *(float4*)&Bs[nxt][sbk][sbt]     = x0;
            *(float4*)&Bs[nxt][sbk][sbt + 4] = x1;
        }
        __syncthreads();
    }

    const int flag = (int)FLG[0];
    for (int fi = 0; fi < 2; ++fi)
    for (int h = 0; h < 4; ++h)
    for (int v = 0; v < 4; ++v) {
        int rl, cl;
        frag_rc(flag, lk, lr, v, rl, cl);
        const int f = m0 + wf + fi * 16 + rl;
        if (f >= 500) continue;
        const int tloc = tt0 + wt + h * 16 + cl;
        const double bm = (double)B1[f];
        const double bl = (double)B1[500 + f];
        const double mu = fmax(accm[fi][h][v] + bm, 0.0);
        const double lv = fmax(accl[fi][h][v] + bl, 0.0);
        const double e  = (double)EPS[((size_t)b * 500 + f) * 512 + t0 + tloc];
        SAMP[((size_t)b * 500 + f) * TCG + tloc] = mu + e * exp(0.5 * lv);
    }
}

// ---------------------------------------------------------------------------
// iir2: exact sequential dual-exp, in-place on (32000 rows, TCG).
// ---------------------------------------------------------------------------
__global__ __launch_bounds__(256) void iir2_chunk(
    double* __restrict__ A,
    double* __restrict__ stM, double* __restrict__ stS, int first)
{
    __shared__ double tile[64][65];
    const int tid = threadIdx.x;
    const int r0 = blockIdx.x * 64;
    double m = 0.0, s = 0.0;
    if (tid < 64 && !first) { m = stM[r0 + tid]; s = stS[r0 + tid]; }

    for (int sub = 0; sub < TCG / 64; ++sub) {
        #pragma unroll
        for (int q = 0; q < 8; ++q) {
            const int e2 = q * 256 + tid;
            const int r = e2 >> 5;
            const int c = (e2 & 31) * 2;
            const double2 v = *(const double2*)&A[(size_t)(r0 + r) * TCG + sub * 64 + c];
            tile[r][c] = v.x; tile[r][c + 1] = v.y;
        }
        __syncthreads();
        if (tid < 64) {
            #pragma unroll
            for (int c = 0; c < 64; ++c) {
                const double x = tile[tid][c];
                m = EMD * m + x;
                s = ESD * s + x;
                tile[tid][c] = m - s;
            }
        }
        __syncthreads();
        #pragma unroll
        for (int q = 0; q < 8; ++q) {
            const int e2 = q * 256 + tid;
            const int r = e2 >> 5;
            const int c = (e2 & 31) * 2;
            double2 v; v.x = tile[r][c]; v.y = tile[r][c + 1];
            *(double2*)&A[(size_t)(r0 + r) * TCG + sub * 64 + c] = v;
        }
        __syncthreads();
    }
    if (tid < 64) { stM[r0 + tid] = m; stS[r0 + tid] = s; }
}

// ---------------------------------------------------------------------------
// g2_mfma: wx2[tl,b,o] = sum_f a2[b,f,t_off+tl]*W2[o,f] + B2[o].
// Block 64tl x 128o, 4 waves (wave 32tl x 64o). K=500 pad 512, 32 k-tiles,
// double-buffered. At stride 72 f64; Wo stride 136 f32.
// ---------------------------------------------------------------------------
__global__ __launch_bounds__(256, 2) void g2_mfma(
    const double* __restrict__ A2,  // (64,500,TCG)
    const float* __restrict__ W2,   // (500,500)
    const float* __restrict__ B2,   // (500)
    double* __restrict__ WX2,       // (TCS,64,500)
    const double* __restrict__ FLG,
    int t_off)
{
    const int b   = blockIdx.z;
    const int o0  = blockIdx.y * 128;
    const int tl0 = blockIdx.x * 64;

    __shared__ double At[2][16][72];
    __shared__ float  Wo[2][16][136];

    const int tid  = threadIdx.x;
    const int lane = tid & 63;
    const int wid  = tid >> 6;
    const int wtl  = (wid >> 1) * 32;       // {0,32}
    const int wo   = (wid & 1) * 64;        // {0,64}
    const int lr   = lane & 15;
    const int lk   = lane >> 4;

    // staging assignment
    const int akk = tid >> 4;               // 0..15 f-offset
    const int at4 = (tid & 15) * 4;         // tl offset
    const double* a_ptr = &A2[((size_t)b * 500 + akk) * TCG + t_off + tl0 + at4];
    const int woo = tid & 127;              // o offset
    const int wfc = (tid >> 7) * 8;         // f sub-offset {0,8}
    int so = o0 + woo; if (so > 499) so = 499;
    const float* w_ptr = &W2[(size_t)so * 500 + wfc];

    d4 acc[2][4] = {};

    {   // stage k-tile 0 (k0 = 0; all f < 500)
        const double2 v0 = *(const double2*)a_ptr;
        const double2 v1 = *(const double2*)(a_ptr + 2);
        *(double2*)&At[0][akk][at4]     = v0;
        *(double2*)&At[0][akk][at4 + 2] = v1;
        const float4 w0 = *(const float4*)w_ptr;
        const float4 w1 = *(const float4*)(w_ptr + 4);
        Wo[0][wfc+0][woo] = w0.x; Wo[0][wfc+1][woo] = w0.y;
        Wo[0][wfc+2][woo] = w0.z; Wo[0][wfc+3][woo] = w0.w;
        Wo[0][wfc+4][woo] = w1.x; Wo[0][wfc+5][woo] = w1.y;
        Wo[0][wfc+6][woo] = w1.z; Wo[0][wfc+7][woo] = w1.w;
    }
    __syncthreads();

    for (int it = 0; it < 32; ++it) {
        const int cur = it & 1;
        double2 v0, v1; float wr[8];
        if (it < 31) {
            const int k0n = (it + 1) * 16;
            if (k0n + akk < 500) {
                v0 = *(const double2*)(a_ptr + (size_t)k0n * TCG);
                v1 = *(const double2*)(a_ptr + (size_t)k0n * TCG + 2);
            } else { v0.x = v0.y = v1.x = v1.y = 0.0; }
            if (k0n + wfc + 7 < 500) {
                const float4 w0 = *(const float4*)(w_ptr + k0n);
                const float4 w1 = *(const float4*)(w_ptr + k0n + 4);
                wr[0]=w0.x; wr[1]=w0.y; wr[2]=w0.z; wr[3]=w0.w;
                wr[4]=w1.x; wr[5]=w1.y; wr[6]=w1.z; wr[7]=w1.w;
            } else {
                #pragma unroll
                for (int c = 0; c < 8; ++c)
                    wr[c] = (k0n + wfc + c < 500) ? w_ptr[k0n + c] : 0.0f;
            }
        }
        #pragma unroll
        for (int ks = 0; ks < 4; ++ks) {
            const int kr = 4 * ks + lk;
            const double a0 = At[cur][kr][wtl + lr];
            const double a1 = At[cur][kr][wtl + 16 + lr];
            double ww[4];
            #pragma unroll
            for (int h = 0; h < 4; ++h)
                ww[h] = (double)Wo[cur][kr][wo + 16 * h + lr];
            #pragma unroll
            for (int h = 0; h < 4; ++h) {
                acc[0][h] = __builtin_amdgcn_mfma_f64_16x16x4f64(a0, ww[h], acc[0][h], 0, 0, 0);
                acc[1][h] = __builtin_amdgcn_mfma_f64_16x16x4f64(a1, ww[h], acc[1][h], 0, 0, 0);
            }
        }
        __syncthreads();
        if (it < 31) {
            const int nxt = cur ^ 1;
            *(double2*)&At[nxt][akk][at4]     = v0;
            *(double2*)&At[nxt][akk][at4 + 2] = v1;
            Wo[nxt][wfc+0][woo] = wr[0]; Wo[nxt][wfc+1][woo] = wr[1];
            Wo[nxt][wfc+2][woo] = wr[2]; Wo[nxt][wfc+3][woo] = wr[3];
            Wo[nxt][wfc+4][woo] = wr[4]; Wo[nxt][wfc+5][woo] = wr[5];
            Wo[nxt][wfc+6][woo] = wr[6]; Wo[nxt][wfc+7][woo] = wr[7];
        }
        __syncthreads();
    }

    const int flag = (int)FLG[0];
    for (int fi = 0; fi < 2; ++fi)
    for (int h = 0; h < 4; ++h)
    for (int v = 0; v < 4; ++v) {
        int rl, cl;
        frag_rc(flag, lk, lr, v, rl, cl);
        const int tl = tl0 + wtl + fi * 16 + rl;
        const int o  = o0 + wo + h * 16 + cl;
        if (o < 500)
            WX2[((size_t)tl * 64 + b) * 500 + o] = acc[fi][h][v] + (double)B2[o];
    }
}

// ---------------------------------------------------------------------------
// LIF2 + IIR3 fused, in-place on (TCS, 32000); carries (v, sp, m, s).
// ---------------------------------------------------------------------------
__global__ __launch_bounds__(256) void lif2iir3_chunk(
    double* __restrict__ WX,
    double* __restrict__ stV, double* __restrict__ stSp,
    double* __restrict__ stM, double* __restrict__ stS, int first)
{
    const int idx = blockIdx.x * 256 + threadIdx.x;
    if (idx >= 32000) return;
    double v, sp, m, s;
    if (first) { v = 0.0; sp = 0.0; m = 0.0; s = 0.0; }
    else { v = stV[idx]; sp = stSp[idx]; m = stM[idx]; s = stS[idx]; }
    for (int tt = 0; tt < TCS; ++tt) {
        const double cur = WX[(size_t)tt * 32000 + idx];
        v = EMD * v * (1.0 - sp) + cur;
        sp = (v >= 1.0) ? 1.0 : 0.0;
        m = EMD * m + sp;
        s = ESD * s + sp;
        WX[(size_t)tt * 32000 + idx] = m - s;
    }
    stV[idx] = v; stSp[idx] = sp; stM[idx] = m; stS[idx] = s;
}

// ---------------------------------------------------------------------------
// g3: one wave per R; lanes split K, 10 outputs tree-reduced via shfl_xor.
// ---------------------------------------------------------------------------
__global__ __launch_bounds__(256) void g3_chunk(
    const double* __restrict__ A3,  // (64*TCS, 500)
    const float* __restrict__ W3,   // (10,500)
    const float* __restrict__ B3,   // (10)
    double* __restrict__ WX3)       // (64*TCS, 10)
{
    __shared__ float w3s[5000];
    for (int i = threadIdx.x; i < 5000; i += 256) w3s[i] = W3[i];
    __syncthreads();

    const int lane = threadIdx.x & 63;
    const int R = blockIdx.x * 4 + (threadIdx.x >> 6);   // 0..8191
    const double* row = A3 + (size_t)R * 500;

    double p[10] = {};
    #pragma unroll
    for (int c = 0; c < 8; ++c) {
        const int i = c * 64 + lane;
        const int ii = (i < 500) ? i : 0;
        const double x = (i < 500) ? row[ii] : 0.0;
        #pragma unroll
        for (int o = 0; o < 10; ++o)
            p[o] = fma(x, (double)w3s[o * 500 + ii], p[o]);
    }
    #pragma unroll
    for (int off = 32; off; off >>= 1)
        #pragma unroll
        for (int o = 0; o < 10; ++o)
            p[o] += __shfl_xor(p[o], off, 64);
    if (lane < 10)
        WX3[(size_t)R * 10 + lane] = p[lane] + (double)B3[lane];
}

// ---------------------------------------------------------------------------
// lif3: (tt*640+idx) -> OUT[idx*512 + t0+tt]; carries (v, sp).
// ---------------------------------------------------------------------------
__global__ __launch_bounds__(256) void lif3_chunk(
    const double* __restrict__ WX3, float* __restrict__ OUT,
    double* __restrict__ stV, double* __restrict__ stSp, int first, int t0)
{
    const int idx = blockIdx.x * 256 + threadIdx.x;
    if (idx >= 640) return;
    double v = first ? 0.0 : stV[idx];
    double sp = first ? 0.0 : stSp[idx];
    for (int tt = 0; tt < TCS; ++tt) {
        const double cur = WX3[(size_t)tt * 640 + idx];
        v = EMD * v * (1.0 - sp) + cur;
        sp = (v >= 1.0) ? 1.0 : 0.0;
        OUT[(size_t)idx * 512 + t0 + tt] = (float)sp;
    }
    stV[idx] = v; stSp[idx] = sp;
}

__global__ void sent_kernel(float* __restrict__ OUT, float v) { OUT[0] = v; }

// ---------------------------------------------------------------------------
extern "C" void kernel_launch(void* const* d_in, const int* in_sizes, int n_in,
                              void* d_out, int out_size, void* d_ws, size_t ws_size,
                              hipStream_t stream)
{
    float* OUT = (float*)d_out;

    const int expect[8] = {25690112, 16384000, 784000, 1000, 250000, 500, 5000, 10};
    int bad = -1;
    if (n_in != 8) bad = 0;
    else {
        for (int k = 0; k < 8; ++k)
            if (in_sizes[k] != expect[k]) { bad = 1 + k; break; }
        if (bad < 0 && out_size != 327680) bad = 9;
        if (bad < 0 && ws_size < (size_t)131072000) bad = 10;
    }
    if (bad >= 0) {
        sent_kernel<<<1, 1, 0, stream>>>(OUT, 4100.0f + bad);
        return;
    }

    const float* X   = (const float*)d_in[0];
    const float* EPS = (const float*)d_in[1];
    const float* W1  = (const float*)d_in[2];
    const float* B1  = (const float*)d_in[3];
    const float* W2  = (const float*)d_in[4];
    const float* B2  = (const float*)d_in[5];
    const float* W3  = (const float*)d_in[6];
    const float* B3  = (const float*)d_in[7];

    double* ws = (double*)d_ws;
    double* buf1  = ws;               // (64,500,TCG)  8,192,000 doubles
    double* buf2  = ws + 8192000;     // (TCS,64,500)  4,096,000
    double* buf4  = ws + 12288000;    // (64*TCS,10)      81,920
    double* stM2  = ws + 12400000;    // 32,000 each
    double* stS2  = ws + 12432000;
    double* stV2  = ws + 12464000;
    double* stSp2 = ws + 12496000;
    double* stM3  = ws + 12528000;
    double* stS3  = ws + 12560000;
    double* stV3  = ws + 12592000;    // 640 each
    double* stSp3 = ws + 12593000;
    double* FLG   = ws + 12600000;    // MFMA layout flag

    mfma_probe<<<1, 64, 0, stream>>>(FLG);

    for (int tc = 0; tc < 512 / TCG; ++tc) {
        const int t0 = tc * TCG;
        const int firstc = (tc == 0) ? 1 : 0;
        g1_mfma<<<dim3(TCG / 128, 8, 64), 256, 0, stream>>>(X, W1, B1, EPS, buf1, FLG, t0);
        iir2_chunk<<<500, 256, 0, stream>>>(buf1, stM2, stS2, firstc);
        for (int h = 0; h < TCG / TCS; ++h) {
            const int first = (firstc && h == 0) ? 1 : 0;
            g2_mfma<<<dim3(TCS / 64, 4, 64), 256, 0, stream>>>(buf1, W2, B2, buf2, FLG, h * TCS);
            lif2iir3_chunk<<<125, 256, 0, stream>>>(buf2, stV2, stSp2, stM3, stS3, first);
            g3_chunk<<<2048, 256, 0, stream>>>(buf2, W3, B3, buf4);
            lif3_chunk<<<3, 256, 0, stream>>>(buf4, OUT, stV3, stSp3, first, t0 + h * TCS);
        }
    }
}

// Round 12
// 1415.269 us; speedup vs baseline: 3.2970x; 3.2662x over previous
//
#include <hip/hip_runtime.h>

#define EMD 0.77880078307140486824  // exp(-1/4)
#define ESD 0.36787944117144232160  // exp(-1)
#define TCG 256                     // g1/iir2 chunk (2 chunks of 512)
#define TCS 128                     // downstream sub-chunk

typedef double d4 __attribute__((ext_vector_type(4)));

// ---------------------------------------------------------------------------
// MFMA f64 16x16x4 C/D-layout probe (verified working in round 9).
// ---------------------------------------------------------------------------
__global__ void mfma_probe(double* __restrict__ flagOut)
{
    const int lane = threadIdx.x & 63;
    const int lr = lane & 15;
    const int lk = lane >> 4;
    const double a = 100.0 * lr + lk + 1.0;
    const double b = 1000.0 * lk + lr + 7.0;
    d4 c = {};
    c = __builtin_amdgcn_mfma_f64_16x16x4f64(a, b, c, 0, 0, 0);
    int myflag = 4;
    for (int h = 3; h >= 0; --h) {
        int ok = 1;
        for (int v = 0; v < 4; ++v) {
            int i, j;
            if (h == 0)      { i = 4 * lk + v; j = lr; }
            else if (h == 1) { i = lk + 4 * v; j = lr; }
            else if (h == 2) { i = lr; j = 4 * lk + v; }
            else             { i = lr; j = lk + 4 * v; }
            double e = 0.0;
            for (int k = 0; k < 4; ++k)
                e += (100.0 * i + k + 1.0) * (1000.0 * k + j + 7.0);
            if (c[v] != e) ok = 0;
        }
        if (__all(ok)) myflag = h;
    }
    if (lane == 0) flagOut[0] = (double)myflag;
}

__device__ __forceinline__ void frag_rc(int flag, int lk, int lr, int v,
                                        int& rl, int& cl)
{
    if (flag == 1)      { rl = lk + 4 * v; cl = lr; }
    else if (flag == 2) { rl = lr; cl = 4 * lk + v; }
    else if (flag == 3) { rl = lr; cl = lk + 4 * v; }
    else                { rl = 4 * lk + v; cl = lr; }
}

// ---------------------------------------------------------------------------
// g1_mfma: block = 4 waves, tile 64f x 128t; wave = 32f x 64t for BOTH mu
// and lv. K=784, 49 k-tiles of 16, double-buffered LDS + reg prefetch.
// CRITICAL (rule #20 / round-11 lesson): every loop indexing accm/accl MUST
// be #pragma unroll'd, else the d4 arrays are allocated in scratch and every
// MFMA round-trips HBM (6.6 GB/dispatch of spill writes, MfmaUtil 16%).
// __launch_bounds__(256,2): 256-VGPR budget for the ~190-reg working set.
// ---------------------------------------------------------------------------
__global__ __launch_bounds__(256, 2) void g1_mfma(
    const float* __restrict__ X,    // (64,784,512)
    const float* __restrict__ W1,   // (1000,784)
    const float* __restrict__ B1,   // (1000)
    const float* __restrict__ EPS,  // (64,500,512)
    double* __restrict__ SAMP,      // (64,500,TCG)
    const double* __restrict__ FLG,
    int t0)
{
    const int b   = blockIdx.z;
    const int m0  = blockIdx.y * 64;
    const int tt0 = blockIdx.x * 128;       // within TCG chunk
    const int tg  = t0 + tt0;

    __shared__ float Am[2][16][80];
    __shared__ float Al[2][16][80];
    __shared__ float Bs[2][16][136];

    const int tid  = threadIdx.x;
    const int lane = tid & 63;
    const int wid  = tid >> 6;
    const int wf   = (wid >> 1) * 32;       // {0,32}
    const int wt   = (wid & 1) * 64;        // {0,64}
    const int lr   = lane & 15;
    const int lk   = lane >> 4;

    // staging assignment
    const int sm  = tid >> 2;               // 0..63 f-row
    const int skk = (tid & 3) * 4;          // 0,4,8,12
    int sf = m0 + sm; if (sf > 499) sf = 499;
    const float* wa_ptr = &W1[(size_t)sf * 784 + skk];
    const float* wl_ptr = &W1[(size_t)(500 + sf) * 784 + skk];
    const int sbk = tid >> 4;               // 0..15
    const int sbt = (tid & 15) * 8;
    const float* x_ptr = &X[((size_t)b * 784 + sbk) * 512 + tg + sbt];

    d4 accm[2][4] = {};
    d4 accl[2][4] = {};

    {   // stage k-tile 0 into buffer 0
        const float4 aw = *(const float4*)wa_ptr;
        const float4 lw = *(const float4*)wl_ptr;
        Am[0][skk+0][sm] = aw.x; Am[0][skk+1][sm] = aw.y;
        Am[0][skk+2][sm] = aw.z; Am[0][skk+3][sm] = aw.w;
        Al[0][skk+0][sm] = lw.x; Al[0][skk+1][sm] = lw.y;
        Al[0][skk+2][sm] = lw.z; Al[0][skk+3][sm] = lw.w;
        *(float4*)&Bs[0][sbk][sbt]     = *(const float4*)x_ptr;
        *(float4*)&Bs[0][sbk][sbt + 4] = *(const float4*)(x_ptr + 4);
    }
    __syncthreads();

    for (int it = 0; it < 49; ++it) {
        const int cur = it & 1;
        float4 aw, lw, x0, x1;
        if (it < 48) {                       // prefetch next k-tile to regs
            const int ko = (it + 1) * 16;
            aw = *(const float4*)(wa_ptr + ko);
            lw = *(const float4*)(wl_ptr + ko);
            x0 = *(const float4*)(x_ptr + (size_t)ko * 512);
            x1 = *(const float4*)(x_ptr + (size_t)ko * 512 + 4);
        }
        #pragma unroll
        for (int ks = 0; ks < 4; ++ks) {
            const int kr = 4 * ks + lk;
            const double a0 = (double)Am[cur][kr][wf + lr];
            const double a1 = (double)Am[cur][kr][wf + 16 + lr];
            const double l0 = (double)Al[cur][kr][wf + lr];
            const double l1 = (double)Al[cur][kr][wf + 16 + lr];
            double bb[4];
            #pragma unroll
            for (int h = 0; h < 4; ++h)
                bb[h] = (double)Bs[cur][kr][wt + 16 * h + lr];
            #pragma unroll
            for (int h = 0; h < 4; ++h) {
                accm[0][h] = __builtin_amdgcn_mfma_f64_16x16x4f64(a0, bb[h], accm[0][h], 0, 0, 0);
                accm[1][h] = __builtin_amdgcn_mfma_f64_16x16x4f64(a1, bb[h], accm[1][h], 0, 0, 0);
                accl[0][h] = __builtin_amdgcn_mfma_f64_16x16x4f64(l0, bb[h], accl[0][h], 0, 0, 0);
                accl[1][h] = __builtin_amdgcn_mfma_f64_16x16x4f64(l1, bb[h], accl[1][h], 0, 0, 0);
            }
        }
        __syncthreads();
        if (it < 48) {
            const int nxt = cur ^ 1;
            Am[nxt][skk+0][sm] = aw.x; Am[nxt][skk+1][sm] = aw.y;
            Am[nxt][skk+2][sm] = aw.z; Am[nxt][skk+3][sm] = aw.w;
            Al[nxt][skk+0][sm] = lw.x; Al[nxt][skk+1][sm] = lw.y;
            Al[nxt][skk+2][sm] = lw.z; Al[nxt][skk+3][sm] = lw.w;
            *(float4*)&Bs[nxt][sbk][sbt]     = x0;
            *(float4*)&Bs[nxt][sbk][sbt + 4] = x1;
        }
        __syncthreads();
    }

    const int flag = (int)FLG[0];
    #pragma unroll
    for (int fi = 0; fi < 2; ++fi)
    {
        #pragma unroll
        for (int h = 0; h < 4; ++h)
        {
            #pragma unroll
            for (int v = 0; v < 4; ++v) {
                int rl, cl;
                frag_rc(flag, lk, lr, v, rl, cl);
                const int f = m0 + wf + fi * 16 + rl;
                if (f >= 500) continue;
                const int tloc = tt0 + wt + h * 16 + cl;
                const double bm = (double)B1[f];
                const double bl = (double)B1[500 + f];
                const double mu = fmax(accm[fi][h][v] + bm, 0.0);
                const double lv = fmax(accl[fi][h][v] + bl, 0.0);
                const double e  = (double)EPS[((size_t)b * 500 + f) * 512 + t0 + tloc];
                SAMP[((size_t)b * 500 + f) * TCG + tloc] = mu + e * exp(0.5 * lv);
            }
        }
    }
}

// ---------------------------------------------------------------------------
// iir2: exact sequential dual-exp, in-place on (32000 rows, TCG).
// ---------------------------------------------------------------------------
__global__ __launch_bounds__(256) void iir2_chunk(
    double* __restrict__ A,
    double* __restrict__ stM, double* __restrict__ stS, int first)
{
    __shared__ double tile[64][65];
    const int tid = threadIdx.x;
    const int r0 = blockIdx.x * 64;
    double m = 0.0, s = 0.0;
    if (tid < 64 && !first) { m = stM[r0 + tid]; s = stS[r0 + tid]; }

    for (int sub = 0; sub < TCG / 64; ++sub) {
        #pragma unroll
        for (int q = 0; q < 8; ++q) {
            const int e2 = q * 256 + tid;
            const int r = e2 >> 5;
            const int c = (e2 & 31) * 2;
            const double2 v = *(const double2*)&A[(size_t)(r0 + r) * TCG + sub * 64 + c];
            tile[r][c] = v.x; tile[r][c + 1] = v.y;
        }
        __syncthreads();
        if (tid < 64) {
            #pragma unroll
            for (int c = 0; c < 64; ++c) {
                const double x = tile[tid][c];
                m = EMD * m + x;
                s = ESD * s + x;
                tile[tid][c] = m - s;
            }
        }
        __syncthreads();
        #pragma unroll
        for (int q = 0; q < 8; ++q) {
            const int e2 = q * 256 + tid;
            const int r = e2 >> 5;
            const int c = (e2 & 31) * 2;
            double2 v; v.x = tile[r][c]; v.y = tile[r][c + 1];
            *(double2*)&A[(size_t)(r0 + r) * TCG + sub * 64 + c] = v;
        }
        __syncthreads();
    }
    if (tid < 64) { stM[r0 + tid] = m; stS[r0 + tid] = s; }
}

// ---------------------------------------------------------------------------
// g2_mfma: wx2[tl,b,o] = sum_f a2[b,f,t_off+tl]*W2[o,f] + B2[o].
// Block 64tl x 128o, 4 waves (wave 32tl x 64o). K=500 pad 512, 32 k-tiles,
// double-buffered. Epilogue fully unrolled (rule #20).
// ---------------------------------------------------------------------------
__global__ __launch_bounds__(256, 2) void g2_mfma(
    const double* __restrict__ A2,  // (64,500,TCG)
    const float* __restrict__ W2,   // (500,500)
    const float* __restrict__ B2,   // (500)
    double* __restrict__ WX2,       // (TCS,64,500)
    const double* __restrict__ FLG,
    int t_off)
{
    const int b   = blockIdx.z;
    const int o0  = blockIdx.y * 128;
    const int tl0 = blockIdx.x * 64;

    __shared__ double At[2][16][72];
    __shared__ float  Wo[2][16][136];

    const int tid  = threadIdx.x;
    const int lane = tid & 63;
    const int wid  = tid >> 6;
    const int wtl  = (wid >> 1) * 32;       // {0,32}
    const int wo   = (wid & 1) * 64;        // {0,64}
    const int lr   = lane & 15;
    const int lk   = lane >> 4;

    // staging assignment
    const int akk = tid >> 4;               // 0..15 f-offset
    const int at4 = (tid & 15) * 4;         // tl offset
    const double* a_ptr = &A2[((size_t)b * 500 + akk) * TCG + t_off + tl0 + at4];
    const int woo = tid & 127;              // o offset
    const int wfc = (tid >> 7) * 8;         // f sub-offset {0,8}
    int so = o0 + woo; if (so > 499) so = 499;
    const float* w_ptr = &W2[(size_t)so * 500 + wfc];

    d4 acc[2][4] = {};

    {   // stage k-tile 0 (k0 = 0; all f < 500)
        const double2 v0 = *(const double2*)a_ptr;
        const double2 v1 = *(const double2*)(a_ptr + 2);
        *(double2*)&At[0][akk][at4]     = v0;
        *(double2*)&At[0][akk][at4 + 2] = v1;
        const float4 w0 = *(const float4*)w_ptr;
        const float4 w1 = *(const float4*)(w_ptr + 4);
        Wo[0][wfc+0][woo] = w0.x; Wo[0][wfc+1][woo] = w0.y;
        Wo[0][wfc+2][woo] = w0.z; Wo[0][wfc+3][woo] = w0.w;
        Wo[0][wfc+4][woo] = w1.x; Wo[0][wfc+5][woo] = w1.y;
        Wo[0][wfc+6][woo] = w1.z; Wo[0][wfc+7][woo] = w1.w;
    }
    __syncthreads();

    for (int it = 0; it < 32; ++it) {
        const int cur = it & 1;
        double2 v0, v1; float wr[8];
        if (it < 31) {
            const int k0n = (it + 1) * 16;
            if (k0n + akk < 500) {
                v0 = *(const double2*)(a_ptr + (size_t)k0n * TCG);
                v1 = *(const double2*)(a_ptr + (size_t)k0n * TCG + 2);
            } else { v0.x = v0.y = v1.x = v1.y = 0.0; }
            if (k0n + wfc + 7 < 500) {
                const float4 w0 = *(const float4*)(w_ptr + k0n);
                const float4 w1 = *(const float4*)(w_ptr + k0n + 4);
                wr[0]=w0.x; wr[1]=w0.y; wr[2]=w0.z; wr[3]=w0.w;
                wr[4]=w1.x; wr[5]=w1.y; wr[6]=w1.z; wr[7]=w1.w;
            } else {
                #pragma unroll
                for (int c = 0; c < 8; ++c)
                    wr[c] = (k0n + wfc + c < 500) ? w_ptr[k0n + c] : 0.0f;
            }
        }
        #pragma unroll
        for (int ks = 0; ks < 4; ++ks) {
            const int kr = 4 * ks + lk;
            const double a0 = At[cur][kr][wtl + lr];
            const double a1 = At[cur][kr][wtl + 16 + lr];
            double ww[4];
            #pragma unroll
            for (int h = 0; h < 4; ++h)
                ww[h] = (double)Wo[cur][kr][wo + 16 * h + lr];
            #pragma unroll
            for (int h = 0; h < 4; ++h) {
                acc[0][h] = __builtin_amdgcn_mfma_f64_16x16x4f64(a0, ww[h], acc[0][h], 0, 0, 0);
                acc[1][h] = __builtin_amdgcn_mfma_f64_16x16x4f64(a1, ww[h], acc[1][h], 0, 0, 0);
            }
        }
        __syncthreads();
        if (it < 31) {
            const int nxt = cur ^ 1;
            *(double2*)&At[nxt][akk][at4]     = v0;
            *(double2*)&At[nxt][akk][at4 + 2] = v1;
            Wo[nxt][wfc+0][woo] = wr[0]; Wo[nxt][wfc+1][woo] = wr[1];
            Wo[nxt][wfc+2][woo] = wr[2]; Wo[nxt][wfc+3][woo] = wr[3];
            Wo[nxt][wfc+4][woo] = wr[4]; Wo[nxt][wfc+5][woo] = wr[5];
            Wo[nxt][wfc+6][woo] = wr[6]; Wo[nxt][wfc+7][woo] = wr[7];
        }
        __syncthreads();
    }

    const int flag = (int)FLG[0];
    #pragma unroll
    for (int fi = 0; fi < 2; ++fi)
    {
        #pragma unroll
        for (int h = 0; h < 4; ++h)
        {
            #pragma unroll
            for (int v = 0; v < 4; ++v) {
                int rl, cl;
                frag_rc(flag, lk, lr, v, rl, cl);
                const int tl = tl0 + wtl + fi * 16 + rl;
                const int o  = o0 + wo + h * 16 + cl;
                if (o < 500)
                    WX2[((size_t)tl * 64 + b) * 500 + o] = acc[fi][h][v] + (double)B2[o];
            }
        }
    }
}

// ---------------------------------------------------------------------------
// LIF2 + IIR3 fused, in-place on (TCS, 32000); carries (v, sp, m, s).
// ---------------------------------------------------------------------------
__global__ __launch_bounds__(256) void lif2iir3_chunk(
    double* __restrict__ WX,
    double* __restrict__ stV, double* __restrict__ stSp,
    double* __restrict__ stM, double* __restrict__ stS, int first)
{
    const int idx = blockIdx.x * 256 + threadIdx.x;
    if (idx >= 32000) return;
    double v, sp, m, s;
    if (first) { v = 0.0; sp = 0.0; m = 0.0; s = 0.0; }
    else { v = stV[idx]; sp = stSp[idx]; m = stM[idx]; s = stS[idx]; }
    for (int tt = 0; tt < TCS; ++tt) {
        const double cur = WX[(size_t)tt * 32000 + idx];
        v = EMD * v * (1.0 - sp) + cur;
        sp = (v >= 1.0) ? 1.0 : 0.0;
        m = EMD * m + sp;
        s = ESD * s + sp;
        WX[(size_t)tt * 32000 + idx] = m - s;
    }
    stV[idx] = v; stSp[idx] = sp; stM[idx] = m; stS[idx] = s;
}

// ---------------------------------------------------------------------------
// g3: one wave per R; lanes split K, 10 outputs tree-reduced via shfl_xor.
// ---------------------------------------------------------------------------
__global__ __launch_bounds__(256) void g3_chunk(
    const double* __restrict__ A3,  // (64*TCS, 500)
    const float* __restrict__ W3,   // (10,500)
    const float* __restrict__ B3,   // (10)
    double* __restrict__ WX3)       // (64*TCS, 10)
{
    __shared__ float w3s[5000];
    for (int i = threadIdx.x; i < 5000; i += 256) w3s[i] = W3[i];
    __syncthreads();

    const int lane = threadIdx.x & 63;
    const int R = blockIdx.x * 4 + (threadIdx.x >> 6);   // 0..8191
    const double* row = A3 + (size_t)R * 500;

    double p[10] = {};
    #pragma unroll
    for (int c = 0; c < 8; ++c) {
        const int i = c * 64 + lane;
        const int ii = (i < 500) ? i : 0;
        const double x = (i < 500) ? row[ii] : 0.0;
        #pragma unroll
        for (int o = 0; o < 10; ++o)
            p[o] = fma(x, (double)w3s[o * 500 + ii], p[o]);
    }
    #pragma unroll
    for (int off = 32; off; off >>= 1)
        #pragma unroll
        for (int o = 0; o < 10; ++o)
            p[o] += __shfl_xor(p[o], off, 64);
    if (lane < 10)
        WX3[(size_t)R * 10 + lane] = p[lane] + (double)B3[lane];
}

// ---------------------------------------------------------------------------
// lif3: (tt*640+idx) -> OUT[idx*512 + t0+tt]; carries (v, sp).
// ---------------------------------------------------------------------------
__global__ __launch_bounds__(256) void lif3_chunk(
    const double* __restrict__ WX3, float* __restrict__ OUT,
    double* __restrict__ stV, double* __restrict__ stSp, int first, int t0)
{
    const int idx = blockIdx.x * 256 + threadIdx.x;
    if (idx >= 640) return;
    double v = first ? 0.0 : stV[idx];
    double sp = first ? 0.0 : stSp[idx];
    for (int tt = 0; tt < TCS; ++tt) {
        const double cur = WX3[(size_t)tt * 640 + idx];
        v = EMD * v * (1.0 - sp) + cur;
        sp = (v >= 1.0) ? 1.0 : 0.0;
        OUT[(size_t)idx * 512 + t0 + tt] = (float)sp;
    }
    stV[idx] = v; stSp[idx] = sp;
}

__global__ void sent_kernel(float* __restrict__ OUT, float v) { OUT[0] = v; }

// ---------------------------------------------------------------------------
extern "C" void kernel_launch(void* const* d_in, const int* in_sizes, int n_in,
                              void* d_out, int out_size, void* d_ws, size_t ws_size,
                              hipStream_t stream)
{
    float* OUT = (float*)d_out;

    const int expect[8] = {25690112, 16384000, 784000, 1000, 250000, 500, 5000, 10};
    int bad = -1;
    if (n_in != 8) bad = 0;
    else {
        for (int k = 0; k < 8; ++k)
            if (in_sizes[k] != expect[k]) { bad = 1 + k; break; }
        if (bad < 0 && out_size != 327680) bad = 9;
        if (bad < 0 && ws_size < (size_t)131072000) bad = 10;
    }
    if (bad >= 0) {
        sent_kernel<<<1, 1, 0, stream>>>(OUT, 4100.0f + bad);
        return;
    }

    const float* X   = (const float*)d_in[0];
    const float* EPS = (const float*)d_in[1];
    const float* W1  = (const float*)d_in[2];
    const float* B1  = (const float*)d_in[3];
    const float* W2  = (const float*)d_in[4];
    const float* B2  = (const float*)d_in[5];
    const float* W3  = (const float*)d_in[6];
    const float* B3  = (const float*)d_in[7];

    double* ws = (double*)d_ws;
    double* buf1  = ws;               // (64,500,TCG)  8,192,000 doubles
    double* buf2  = ws + 8192000;     // (TCS,64,500)  4,096,000
    double* buf4  = ws + 12288000;    // (64*TCS,10)      81,920
    double* stM2  = ws + 12400000;    // 32,000 each
    double* stS2  = ws + 12432000;
    double* stV2  = ws + 12464000;
    double* stSp2 = ws + 12496000;
    double* stM3  = ws + 12528000;
    double* stS3  = ws + 12560000;
    double* stV3  = ws + 12592000;    // 640 each
    double* stSp3 = ws + 12593000;
    double* FLG   = ws + 12600000;    // MFMA layout flag

    mfma_probe<<<1, 64, 0, stream>>>(FLG);

    for (int tc = 0; tc < 512 / TCG; ++tc) {
        const int t0 = tc * TCG;
        const int firstc = (tc == 0) ? 1 : 0;
        g1_mfma<<<dim3(TCG / 128, 8, 64), 256, 0, stream>>>(X, W1, B1, EPS, buf1, FLG, t0);
        iir2_chunk<<<500, 256, 0, stream>>>(buf1, stM2, stS2, firstc);
        for (int h = 0; h < TCG / TCS; ++h) {
            const int first = (firstc && h == 0) ? 1 : 0;
            g2_mfma<<<dim3(TCS / 64, 4, 64), 256, 0, stream>>>(buf1, W2, B2, buf2, FLG, h * TCS);
            lif2iir3_chunk<<<125, 256, 0, stream>>>(buf2, stV2, stSp2, stM3, stS3, first);
            g3_chunk<<<2048, 256, 0, stream>>>(buf2, W3, B3, buf4);
            lif3_chunk<<<3, 256, 0, stream>>>(buf4, OUT, stV3, stSp3, first, t0 + h * TCS);
        }
    }
}